// Round 4
// baseline (955.706 us; speedup 1.0000x reference)
//
#include <hip/hip_runtime.h>
#include <math.h>

#define NROWS 32768
#define DDIM 256
#define KEMB 1024
#define BM 16
#define DD 64           // DDIM/4
#define NCH 16          // KEMB / 64

#define OFF_COMMIT 8388608
#define OFF_EMBED  8388609
#define OFF_ENT    8388610
#define OFF_IDX    8388611

// prevent -ffp-contract=fast from fusing this mul into a following add
#define NOFUSE(x) asm volatile("" : "+v"(x))

// ws float layout: [0..1023] avg_prob sums, [1024] H sum, [1025] sqdiff sum,
//                  [1026..2049] cnorm (numpy-pairwise fp32 emulation)

// ---- cnorm: emulate np.sum(cb**2, axis=1) pairwise order bit-exactly ----
// numpy pairwise for n=256: two 128-blocks; each block: 8 accumulators
// r[j] = x[j]; r[j] += x[8t+j] (t=1..15); res = ((r0+r1)+(r2+r3))+((r4+r5)+(r6+r7));
// total = res_block0 + res_block1.  16 lanes per row: lane = 8*h + j.
__global__ __launch_bounds__(256) void vq_prep(const float* __restrict__ cb,
                                               float* __restrict__ ws) {
  int t = blockIdx.x * 256 + threadIdx.x;   // 64 blocks -> t in [0,16384)
  if (t < 1026) ws[t] = 0.0f;
  int row = t >> 4;                          // 0..1023
  int l = t & 15;
  int h = l >> 3, j = l & 7;
  const float* xp = cb + (size_t)row * DDIM + h * 128 + j;
  float x = xp[0];
  float sq = x * x; NOFUSE(sq);
  float r = sq;
#pragma unroll
  for (int tt = 1; tt < 16; ++tt) {
    x = xp[8 * tt];
    sq = x * x; NOFUSE(sq);
    r = r + sq;
  }
  r = r + __shfl_xor(r, 1, 64);   // (r0+r1) etc. (commutative == numpy pairing)
  r = r + __shfl_xor(r, 2, 64);   // (r0+r1)+(r2+r3)
  r = r + __shfl_xor(r, 4, 64);   // + ((r4+r5)+(r6+r7))
  r = r + __shfl_xor(r, 8, 64);   // block0 + block1
  if (l == 0) ws[1026 + row] = r;
}

__global__ __launch_bounds__(256, 2) void vq_main(const float* __restrict__ z,
                                                  const float* __restrict__ cb,
                                                  float* __restrict__ out,
                                                  float* __restrict__ ws) {
  // 80 KB static LDS: zs 16KB + cs 64KB (pacc/red alias cs after the K loop)
  __shared__ __align__(16) unsigned char smem[BM * DD * 16 + 64 * DD * 16];
  float4* zs = reinterpret_cast<float4*>(smem);                   // [16][64] f4
  float4* cs = reinterpret_cast<float4*>(smem + BM * DD * 16);    // [dd][col^dd] f4
  float* pacc = reinterpret_cast<float*>(smem + BM * DD * 16);    // 1024 f (alias cs)
  float* red = reinterpret_cast<float*>(smem + BM * DD * 16 + 4096); // 8 f

  const int tid = threadIdx.x;
  const int tc = tid & 15;   // column-thread 0..15
  const int tr = tid >> 4;   // local row 0..15
  const int nbase = blockIdx.x * BM;
  const float* cnorm = ws + 1026;

  // stage z rows (coalesced 1KB per wave, conflict-free LDS writes)
#pragma unroll
  for (int i = 0; i < 4; ++i) {
    int idx = tid + i * 256;
    int row = idx >> 6;
    int dd = idx & 63;
    zs[row * 64 + dd] =
        *reinterpret_cast<const float4*>(z + (size_t)(nbase + row) * DDIM + dd * 4);
  }

  float v[64];  // this thread's logits: col = ch*64 + 16*(j&3) + tc

#pragma unroll
  for (int ch = 0; ch < NCH; ++ch) {
    const int kbase = ch * 64;
    __syncthreads();  // prev chunk's reads (and zs staging on ch==0) complete
#pragma unroll
    for (int i = 0; i < 16; ++i) {
      int idx = tid + i * 256;
      int col = idx >> 6;   // wave-uniform
      int dd = idx & 63;    // = lane
      float4 val = *reinterpret_cast<const float4*>(
          cb + (size_t)(kbase + col) * DDIM + dd * 4);
      cs[dd * 64 + (col ^ dd)] = val;  // XOR swizzle: bank-even writes & reads
    }
    __syncthreads();

    float4 a0 = {0.f, 0.f, 0.f, 0.f}, a1 = {0.f, 0.f, 0.f, 0.f};
    float4 a2 = {0.f, 0.f, 0.f, 0.f}, a3 = {0.f, 0.f, 0.f, 0.f};
#pragma unroll 8
    for (int dd = 0; dd < 64; ++dd) {
      float4 zv = zs[tr * 64 + dd];
      int b = dd * 64;
      float4 c0 = cs[b + ((tc) ^ dd)];
      float4 c1 = cs[b + ((tc + 16) ^ dd)];
      float4 c2 = cs[b + ((tc + 32) ^ dd)];
      float4 c3 = cs[b + ((tc + 48) ^ dd)];
      a0.x = fmaf(zv.x, c0.x, a0.x); a0.y = fmaf(zv.y, c0.y, a0.y);
      a0.z = fmaf(zv.z, c0.z, a0.z); a0.w = fmaf(zv.w, c0.w, a0.w);
      a1.x = fmaf(zv.x, c1.x, a1.x); a1.y = fmaf(zv.y, c1.y, a1.y);
      a1.z = fmaf(zv.z, c1.z, a1.z); a1.w = fmaf(zv.w, c1.w, a1.w);
      a2.x = fmaf(zv.x, c2.x, a2.x); a2.y = fmaf(zv.y, c2.y, a2.y);
      a2.z = fmaf(zv.z, c2.z, a2.z); a2.w = fmaf(zv.w, c2.w, a2.w);
      a3.x = fmaf(zv.x, c3.x, a3.x); a3.y = fmaf(zv.y, c3.y, a3.y);
      a3.z = fmaf(zv.z, c3.z, a3.z); a3.w = fmaf(zv.w, c3.w, a3.w);
    }
    float d0 = (a0.x + a0.y) + (a0.z + a0.w);
    float d1 = (a1.x + a1.y) + (a1.z + a1.w);
    float d2 = (a2.x + a2.y) + (a2.z + a2.w);
    float d3 = (a3.x + a3.y) + (a3.z + a3.w);
    // logit = -dist/temp + 100*||z||^2 (row-constant shift dropped)
    v[ch * 4 + 0] = 100.0f * (2.0f * d0 - cnorm[kbase + tc]);
    v[ch * 4 + 1] = 100.0f * (2.0f * d1 - cnorm[kbase + tc + 16]);
    v[ch * 4 + 2] = 100.0f * (2.0f * d2 - cnorm[kbase + tc + 32]);
    v[ch * 4 + 3] = 100.0f * (2.0f * d3 - cnorm[kbase + tc + 48]);
  }

  // ---- top-2 argmax (== argmin distance), tie -> smaller index ----
  float m1 = -3.4e38f, m2 = -3.4e38f;
  int c1 = 0;
#pragma unroll
  for (int j = 0; j < 64; ++j) {
    int col = (j >> 2) * 64 + ((j & 3) << 4) + tc;  // ascending per thread
    if (v[j] > m1) { m2 = m1; m1 = v[j]; c1 = col; }
    else if (v[j] > m2) { m2 = v[j]; }
  }
#pragma unroll
  for (int m = 1; m < 16; m <<= 1) {
    float om1 = __shfl_xor(m1, m, 64);
    int   oc1 = __shfl_xor(c1, m, 64);
    float om2 = __shfl_xor(m2, m, 64);
    if (om1 > m1 || (om1 == m1 && oc1 < c1)) {
      m2 = fmaxf(m1, om2); m1 = om1; c1 = oc1;
    } else {
      m2 = fmaxf(om1, m2);
    }
  }
  const float rowmax = m1;
  const int bcol = c1;
  // contested row: top-2 gap below 0.25 logit units (2.5e-3 in distance units,
  // ~25x our phase-1 numerical error bound) -> re-resolved by vq_fix emulation
  const bool danger = (m1 - m2) < 0.25f;

  // ---- softmax stats: Z, sum(p*l) ----
  float S = 0.f, T = 0.f;
#pragma unroll
  for (int j = 0; j < 64; ++j) {
    float e = __expf(v[j] - rowmax);
    S += e;
    T = fmaf(e, v[j], T);
    v[j] = e;  // keep unnormalized probs
  }
#pragma unroll
  for (int m = 1; m < 16; m <<= 1) {
    S += __shfl_xor(S, m, 64);
    T += __shfl_xor(T, m, 64);
  }
  const float invZ = 1.0f / S;
  const float H = rowmax + logf(S) - T * invZ;  // per-row entropy

  // ---- avg_probs accumulation: pacc aliases cs (K loop done) ----
  __syncthreads();
  pacc[tid] = 0.f; pacc[tid + 256] = 0.f; pacc[tid + 512] = 0.f; pacc[tid + 768] = 0.f;
  __syncthreads();
#pragma unroll
  for (int j = 0; j < 64; ++j) {
    float pj = v[j] * invZ;
    pj += __shfl_xor(pj, 16, 64);   // sum over the wave's 4 rows (same col)
    pj += __shfl_xor(pj, 32, 64);
    if ((tid & 63) < 16) {
      int col = (j >> 2) * 64 + ((j & 3) << 4) + tc;
      atomicAdd(&pacc[col], pj);
    }
  }
  __syncthreads();
#pragma unroll
  for (int i = 0; i < 4; ++i) {
    int k = tid + i * 256;
    atomicAdd(&ws[k], pacc[k]);
  }

  // ---- quantized write (straight-through, exact ref op order) + sqdiff ----
  float sq = 0.f;
#pragma unroll
  for (int jj = 0; jj < 4; ++jj) {
    int dd = jj * 16 + tc;
    float4 zv = zs[tr * 64 + dd];
    float4 cv = *reinterpret_cast<const float4*>(cb + (size_t)bcol * DDIM + dd * 4);
    float4 qv;
    qv.x = zv.x + (cv.x - zv.x);
    qv.y = zv.y + (cv.y - zv.y);
    qv.z = zv.z + (cv.z - zv.z);
    qv.w = zv.w + (cv.w - zv.w);
    *reinterpret_cast<float4*>(out + (size_t)(nbase + tr) * DDIM + dd * 4) = qv;
    float dx = cv.x - zv.x; sq = fmaf(dx, dx, sq);
    dx = cv.y - zv.y; sq = fmaf(dx, dx, sq);
    dx = cv.z - zv.z; sq = fmaf(dx, dx, sq);
    dx = cv.w - zv.w; sq = fmaf(dx, dx, sq);
  }

  // index slot doubles as the danger flag for vq_fix: negative => contested
  if (tc == 0)
    out[OFF_IDX + nbase + tr] = danger ? -(float)(bcol + 1) : (float)bcol;

  // ---- block reductions of H and sqdiff ----
  float hv = (tc == 0) ? H : 0.f;
#pragma unroll
  for (int m = 1; m < 64; m <<= 1) {
    hv += __shfl_xor(hv, m, 64);
    sq += __shfl_xor(sq, m, 64);
  }
  int wid = tid >> 6;
  if ((tid & 63) == 0) { red[wid] = hv; red[4 + wid] = sq; }
  __syncthreads();
  if (tid == 0) {
    atomicAdd(&ws[1024], (red[0] + red[1]) + (red[2] + red[3]));
    atomicAdd(&ws[1025], (red[4] + red[5]) + (red[6] + red[7]));
  }
}

// ---- re-resolve contested rows with a bit-level numpy emulation ----
// znorm: numpy pairwise (as vq_prep); dot: sequential ascending-k fp32 FMA
// (BLAS/Eigen microkernel accumulation order); d = (znorm - 2*dot) + cnorm
// in fp32 in the reference's association order; argmin, tie -> smaller index.
__global__ __launch_bounds__(256) void vq_fix(const float* __restrict__ z,
                                              const float* __restrict__ cb,
                                              float* __restrict__ out,
                                              const float* __restrict__ ws) {
  const int lane = threadIdx.x & 63;
  const int gwave = (int)((blockIdx.x * 256 + threadIdx.x) >> 6);
  const int nw = gridDim.x * 4;
  const float* cnorm = ws + 1026;

  for (int row = gwave; row < NROWS; row += nw) {
    float iv = out[OFF_IDX + row];
    if (iv >= 0.0f) continue;           // uncontested (wave-uniform branch)
    int kold = (int)(-iv) - 1;
    const float* zr = z + (size_t)row * DDIM;

    // znorm, numpy pairwise (lanes 0..15 carry the 16 accumulators)
    float r;
    {
      int h = (lane & 15) >> 3, j = lane & 7;
      const float* xp = zr + h * 128 + j;
      float x = xp[0];
      float sq = x * x; NOFUSE(sq);
      r = sq;
#pragma unroll
      for (int tt = 1; tt < 16; ++tt) {
        x = xp[8 * tt];
        sq = x * x; NOFUSE(sq);
        r = r + sq;
      }
    }
    r = r + __shfl_xor(r, 1, 64);
    r = r + __shfl_xor(r, 2, 64);
    r = r + __shfl_xor(r, 4, 64);
    r = r + __shfl_xor(r, 8, 64);
    const float znorm = __shfl(r, 0, 64);

    // emulated distances over all 1024 codes; lane handles k = lane + 64t
    float bd = 3.4e38f;
    int bk = 0;
#pragma unroll 1
    for (int t = 0; t < 16; ++t) {
      int k = lane + t * 64;
      const float* cr = cb + (size_t)k * DDIM;
      float acc = 0.0f;
#pragma unroll 8
      for (int d = 0; d < 256; ++d) acc = fmaf(zr[d], cr[d], acc);
      float dist = (znorm - 2.0f * acc) + cnorm[k];
      if (dist < bd) { bd = dist; bk = k; }   // ascending k: first min kept
    }
#pragma unroll
    for (int m = 1; m < 64; m <<= 1) {
      float od = __shfl_xor(bd, m, 64);
      int   ok = __shfl_xor(bk, m, 64);
      if (od < bd || (od == bd && ok < bk)) { bd = od; bk = ok; }
    }

    if (bk != kold) {
      // rewrite quantized row with the corrected code (same op order)
      const float* cr = cb + (size_t)bk * DDIM;
#pragma unroll
      for (int i = 0; i < 4; ++i) {
        int d0 = lane + i * 64;
        float zd = zr[d0], cd = cr[d0];
        out[(size_t)row * DDIM + d0] = zd + (cd - zd);
      }
    }
    if (lane == 0) out[OFF_IDX + row] = (float)bk;  // clear flag, final index
  }
}

__global__ __launch_bounds__(1024) void vq_final(float* __restrict__ out,
                                                 const float* __restrict__ ws) {
  __shared__ float red[1024];
  int t = threadIdx.x;
  float a = ws[t] * (1.0f / 32768.0f);
  red[t] = a * logf(a + 1e-5f);
  __syncthreads();
  for (int s = 512; s > 0; s >>= 1) {
    if (t < s) red[t] += red[t + s];
    __syncthreads();
  }
  if (t == 0) {
    float avg_entropy = -red[0];
    float sample_entropy = ws[1024] * (1.0f / 32768.0f);
    float m = ws[1025] * (1.0f / 8388608.0f);
    out[OFF_COMMIT] = 0.25f * m;
    out[OFF_EMBED] = m;
    out[OFF_ENT] = 0.1f * (sample_entropy - avg_entropy);
  }
}

extern "C" void kernel_launch(void* const* d_in, const int* in_sizes, int n_in,
                              void* d_out, int out_size, void* d_ws, size_t ws_size,
                              hipStream_t stream) {
  const float* z = (const float*)d_in[0];
  const float* cb = (const float*)d_in[1];
  float* out = (float*)d_out;
  float* ws = (float*)d_ws;

  vq_prep<<<64, 256, 0, stream>>>(cb, ws);
  vq_main<<<NROWS / BM, 256, 0, stream>>>(z, cb, out, ws);
  vq_fix<<<256, 256, 0, stream>>>(z, cb, out, ws);
  vq_final<<<1, 1024, 0, stream>>>(out, ws);
}

// Round 5
// 452.685 us; speedup vs baseline: 2.1112x; 2.1112x over previous
//
#include <hip/hip_runtime.h>
#include <math.h>

#define NROWS 32768
#define DDIM 256
#define KEMB 1024

#define OFF_COMMIT 8388608
#define OFF_EMBED  8388609
#define OFF_ENT    8388610
#define OFF_IDX    8388611

// ws float layout: [0..1023] avg_prob sums, [1024] H sum, [1025] sqdiff sum,
// [1026..2049] cnorm, [4096..266239] cb hi/lo bf16 staging image (1 MB).
#define WS_IMG_F 4096
#define WS_NEED_BYTES ((size_t)(WS_IMG_F + 262144) * 4)

// prevent -ffp-contract=fast from fusing this mul into a following add
#define NOFUSE(x) asm volatile("" : "+v"(x))

typedef __attribute__((ext_vector_type(8))) short bf16x8;
typedef __attribute__((ext_vector_type(16))) float f32x16;
#define MFMA32(a, b, c) __builtin_amdgcn_mfma_f32_32x32x16_bf16((a), (b), (c), 0, 0, 0)

// round-to-nearest-even fp32 -> bf16 hi + bf16 lo split
__device__ inline void bf16split(float x, unsigned short& h, unsigned short& l) {
  unsigned u = __float_as_uint(x);
  unsigned r = u + 0x7FFFu + ((u >> 16) & 1u);
  h = (unsigned short)(r >> 16);
  float hf = __uint_as_float(r & 0xFFFF0000u);
  float lo = x - hf;  // exact (Sterbenz)
  unsigned ul = __float_as_uint(lo);
  unsigned rl = ul + 0x7FFFu + ((ul >> 16) & 1u);
  l = (unsigned short)(rl >> 16);
}

// ---- cnorm: emulate np.sum(cb**2, axis=1) pairwise order bit-exactly ----
__global__ __launch_bounds__(256) void vq_prep(const float* __restrict__ cb,
                                               float* __restrict__ ws) {
  int t = blockIdx.x * 256 + threadIdx.x;  // 64 blocks -> t in [0,16384)
  if (t < 1026) ws[t] = 0.0f;
  int row = t >> 4;  // 0..1023
  int l = t & 15;
  int h = l >> 3, j = l & 7;
  const float* xp = cb + (size_t)row * DDIM + h * 128 + j;
  float x = xp[0];
  float sq = x * x; NOFUSE(sq);
  float r = sq;
#pragma unroll
  for (int tt = 1; tt < 16; ++tt) {
    x = xp[8 * tt];
    sq = x * x; NOFUSE(sq);
    r = r + sq;
  }
  r = r + __shfl_xor(r, 1, 64);
  r = r + __shfl_xor(r, 2, 64);
  r = r + __shfl_xor(r, 4, 64);
  r = r + __shfl_xor(r, 8, 64);
  if (l == 0) ws[1026 + row] = r;
}

// ---- build cb hi/lo bf16 staging image in ws ----
// chunk c = kc*2+half (32 chunks x 32KB). Within chunk (ushort units):
// hi: col'*16 + kb*8 + e ; lo: 8192 + col'*16 + kb*8 + e
// where kg = kc*16 + kb*8 + e, colg = half*512 + col'.
__global__ __launch_bounds__(256) void vq_cbimg(const float* __restrict__ cb,
                                                float* __restrict__ ws) {
  unsigned short* img = (unsigned short*)(ws + WS_IMG_F);
  int t = blockIdx.x * 256 + threadIdx.x;  // 256 blocks -> 65536
  int colg = t >> 6;
  int kg0 = (t & 63) << 2;
  float4 v = *(const float4*)(cb + ((size_t)colg << 8) + kg0);
  unsigned short h0, h1, h2, h3, l0, l1, l2, l3;
  bf16split(v.x, h0, l0); bf16split(v.y, h1, l1);
  bf16split(v.z, h2, l2); bf16split(v.w, h3, l3);
  int kc = kg0 >> 4;
  int kb = (kg0 >> 3) & 1;
  int e0 = kg0 & 7;  // 0 or 4
  int half = colg >> 9;
  int colp = colg & 511;
  int chunk = (kc << 1) | half;
  int base = (chunk << 14) + (colp << 4) + (kb << 3) + e0;
  ushort4 hv; hv.x = h0; hv.y = h1; hv.z = h2; hv.w = h3;
  ushort4 lv; lv.x = l0; lv.y = l1; lv.z = l2; lv.w = l3;
  *(ushort4*)(img + base) = hv;
  *(ushort4*)(img + base + 8192) = lv;
}

// ---- MFMA main: BM=32 rows/block, 512 threads (8 waves), split-bf16 3-pass ----
// LDS: [0,16K) zh, [16K,32K) zl, [32K,64K) cb chunk (hi 16K + lo 16K)
// epilogue alias: [0,4K) pacc, [4K,68K) logits[16][1024], [68K..] red
__global__ __launch_bounds__(512, 2) void vq_main2(const float* __restrict__ z,
                                                   const float* __restrict__ cb,
                                                   const unsigned short* __restrict__ img,
                                                   float* __restrict__ out,
                                                   float* __restrict__ ws) {
  __shared__ __align__(16) unsigned char smem[69888];
  unsigned short* zh_s = (unsigned short*)smem;
  unsigned short* zl_s = (unsigned short*)(smem + 16384);
  const int tid = threadIdx.x;
  const int w = tid >> 6;
  const int lane = tid & 63;
  const int l31 = lane & 31, lhi = lane >> 5;
  const int nbase = blockIdx.x * 32;
  const float* cnorm = ws + 1026;

  // stage z rows: fp32 -> bf16 hi/lo, XOR-swizzled 16B units (u' = u ^ row)
#pragma unroll
  for (int i = 0; i < 16; ++i) {
    int idx = tid + (i << 9);
    int row = idx >> 8, k = idx & 255;
    float x = z[((size_t)(nbase + row) << 8) + k];
    unsigned short hh, ll;
    bf16split(x, hh, ll);
    int uoff = (row << 8) + ((((k >> 3) ^ row) & 31) << 3) + (k & 7);
    zh_s[uoff] = hh; zl_s[uoff] = ll;
  }
  __syncthreads();

  f32x16 acc[4];  // tiles w, w+8, w+16, w+24
#pragma unroll
  for (int t = 0; t < 4; ++t)
#pragma unroll
    for (int e = 0; e < 16; ++e) acc[t][e] = 0.0f;

#pragma unroll 1
  for (int kc = 0; kc < 16; ++kc) {
    // A-frags for this K-step (zh_s static; swizzle u' = (kc*2+lhi) ^ row)
    const int abase = (l31 << 9) | (((((kc << 1) | lhi) ^ l31) & 31) << 4);
    bf16x8 azh = *(const bf16x8*)(smem + abase);
    bf16x8 azl = *(const bf16x8*)(smem + 16384 + abase);
#pragma unroll
    for (int h = 0; h < 2; ++h) {
      // stage chunk (kc,h): pure linear 32KB copy, conflict-free
      const float4* src = (const float4*)((const unsigned char*)img + (((kc << 1) | h) << 15));
      float4 s0 = src[tid];
      float4 s1 = src[tid + 512];
      float4 s2 = src[tid + 1024];
      float4 s3 = src[tid + 1536];
      __syncthreads();  // prev chunk reads done
      float4* dst = (float4*)(smem + 32768);
      dst[tid] = s0; dst[tid + 512] = s1; dst[tid + 1024] = s2; dst[tid + 1536] = s3;
      __syncthreads();  // staged visible
#pragma unroll
      for (int j = 0; j < 2; ++j) {
        const int boff = ((w | (j << 3)) << 10) | (l31 << 5) | (lhi << 4);
        bf16x8 bh = *(const bf16x8*)(smem + 32768 + boff);
        bf16x8 bl = *(const bf16x8*)(smem + 49152 + boff);
        f32x16 a = acc[(h << 1) | j];
        a = MFMA32(azh, bh, a);
        a = MFMA32(azh, bl, a);
        a = MFMA32(azl, bh, a);
        acc[(h << 1) | j] = a;
      }
    }
  }

  // ---- epilogue ----
  __syncthreads();  // all B/A reads done; LDS reused
  float* pacc = (float*)smem;
  float* logits = (float*)(smem + 4096);
  float* redH = (float*)(smem + 69632);
  float* redS = (float*)(smem + 69760);
  pacc[tid] = 0.0f;
  pacc[tid + 512] = 0.0f;
  float cn[4];
#pragma unroll
  for (int I = 0; I < 4; ++I) {
    int gt = w + ((I & 1) << 3) + ((I >> 1) << 4);
    cn[I] = cnorm[(gt << 5) + l31];
  }
  const int erow = tid >> 5, ecl = tid & 31;
#pragma unroll
  for (int h = 0; h < 2; ++h) {
    __syncthreads();  // pacc-zero visible / prev-half logit reads done
    // write logits for local rows 0..15 of this half (C/D layout, m101)
#pragma unroll
    for (int I = 0; I < 4; ++I) {
      int gt = w + ((I & 1) << 3) + ((I >> 1) << 4);
      int col = (gt << 5) + l31;
#pragma unroll
      for (int q = 0; q < 8; ++q) {
        int rowl = (q & 3) | ((q >> 2) << 3) | (lhi << 2);
        logits[(rowl << 10) + col] = 200.0f * acc[I][(h << 3) + q] - 100.0f * cn[I];
      }
    }
    __syncthreads();
    const int grow = nbase + (h << 4) + erow;
    float v2[32];  // cols ecl + 32m, ascending
#pragma unroll
    for (int m = 0; m < 32; ++m) v2[m] = logits[(erow << 10) + ecl + (m << 5)];
    // top-2 argmax (== argmin distance), tie -> smaller index
    float m1 = -3.4e38f, m2v = -3.4e38f;
    int c1 = 0;
#pragma unroll
    for (int m = 0; m < 32; ++m) {
      float val = v2[m];
      if (val > m1) { m2v = m1; m1 = val; c1 = ecl + (m << 5); }
      else if (val > m2v) { m2v = val; }
    }
#pragma unroll
    for (int mk = 1; mk < 32; mk <<= 1) {
      float om1 = __shfl_xor(m1, mk, 64);
      int oc1 = __shfl_xor(c1, mk, 64);
      float om2 = __shfl_xor(m2v, mk, 64);
      if (om1 > m1 || (om1 == m1 && oc1 < c1)) { m2v = fmaxf(m1, om2); m1 = om1; c1 = oc1; }
      else { m2v = fmaxf(om1, m2v); }
    }
    const float rowmax = m1;
    const int bcol = c1;
    const bool danger = (m1 - m2v) < 0.25f;  // ~2500x MFMA-path error bound
    // softmax stats
    float S = 0.f, T = 0.f;
#pragma unroll
    for (int m = 0; m < 32; ++m) {
      float e = __expf(v2[m] - rowmax);
      S += e;
      T = fmaf(e, v2[m], T);
      v2[m] = e;
    }
#pragma unroll
    for (int mk = 1; mk < 32; mk <<= 1) {
      S += __shfl_xor(S, mk, 64);
      T += __shfl_xor(T, mk, 64);
    }
    const float invZ = 1.0f / S;
    const float H = rowmax + logf(S) - T * invZ;
#pragma unroll
    for (int m = 0; m < 32; ++m) atomicAdd(&pacc[ecl + (m << 5)], v2[m] * invZ);
    // quantized write (straight-through, exact ref op order) + sqdiff
    float sq = 0.f;
    const float* zr = z + ((size_t)grow << 8) + (ecl << 3);
    const float* cr = cb + ((size_t)bcol << 8) + (ecl << 3);
    float* orow = out + ((size_t)grow << 8) + (ecl << 3);
#pragma unroll
    for (int u = 0; u < 2; ++u) {
      float4 zv = *(const float4*)(zr + u * 4);
      float4 cv = *(const float4*)(cr + u * 4);
      float4 qv;
      qv.x = zv.x + (cv.x - zv.x);
      qv.y = zv.y + (cv.y - zv.y);
      qv.z = zv.z + (cv.z - zv.z);
      qv.w = zv.w + (cv.w - zv.w);
      *(float4*)(orow + u * 4) = qv;
      float dx = cv.x - zv.x; sq = fmaf(dx, dx, sq);
      dx = cv.y - zv.y; sq = fmaf(dx, dx, sq);
      dx = cv.z - zv.z; sq = fmaf(dx, dx, sq);
      dx = cv.w - zv.w; sq = fmaf(dx, dx, sq);
    }
#pragma unroll
    for (int mk = 1; mk < 32; mk <<= 1) sq += __shfl_xor(sq, mk, 64);
    if (ecl == 0) {
      redH[(h << 4) + erow] = H;
      redS[(h << 4) + erow] = sq;
      out[OFF_IDX + grow] = danger ? -(float)(bcol + 1) : (float)bcol;
    }
  }
  __syncthreads();
  atomicAdd(&ws[tid], pacc[tid]);
  atomicAdd(&ws[tid + 512], pacc[tid + 512]);
  if (tid == 0) {
    float hs = 0.f, ss = 0.f;
#pragma unroll
    for (int i = 0; i < 32; ++i) { hs += redH[i]; ss += redS[i]; }
    atomicAdd(&ws[1024], hs);
    atomicAdd(&ws[1025], ss);
  }
}

// ---- fallback fp32 main (round-4 verified) if ws too small for the image ----
__global__ __launch_bounds__(256, 2) void vq_main_fb(const float* __restrict__ z,
                                                     const float* __restrict__ cb,
                                                     float* __restrict__ out,
                                                     float* __restrict__ ws) {
  __shared__ __align__(16) unsigned char smem[16 * 64 * 16 + 64 * 64 * 16];
  float4* zs = reinterpret_cast<float4*>(smem);
  float4* cs = reinterpret_cast<float4*>(smem + 16 * 64 * 16);
  float* pacc = reinterpret_cast<float*>(smem + 16 * 64 * 16);
  float* red = reinterpret_cast<float*>(smem + 16 * 64 * 16 + 4096);

  const int tid = threadIdx.x;
  const int tc = tid & 15;
  const int tr = tid >> 4;
  const int nbase = blockIdx.x * 16;
  const float* cnorm = ws + 1026;

#pragma unroll
  for (int i = 0; i < 4; ++i) {
    int idx = tid + i * 256;
    int row = idx >> 6;
    int dd = idx & 63;
    zs[row * 64 + dd] =
        *reinterpret_cast<const float4*>(z + (size_t)(nbase + row) * DDIM + dd * 4);
  }

  float v[64];
#pragma unroll
  for (int ch = 0; ch < 16; ++ch) {
    const int kbase = ch * 64;
    __syncthreads();
#pragma unroll
    for (int i = 0; i < 16; ++i) {
      int idx = tid + i * 256;
      int col = idx >> 6;
      int dd = idx & 63;
      float4 val = *reinterpret_cast<const float4*>(
          cb + (size_t)(kbase + col) * DDIM + dd * 4);
      cs[dd * 64 + (col ^ dd)] = val;
    }
    __syncthreads();

    float4 a0 = {0.f, 0.f, 0.f, 0.f}, a1 = {0.f, 0.f, 0.f, 0.f};
    float4 a2 = {0.f, 0.f, 0.f, 0.f}, a3 = {0.f, 0.f, 0.f, 0.f};
#pragma unroll 8
    for (int dd = 0; dd < 64; ++dd) {
      float4 zv = zs[tr * 64 + dd];
      int b = dd * 64;
      float4 c0 = cs[b + ((tc) ^ dd)];
      float4 c1 = cs[b + ((tc + 16) ^ dd)];
      float4 c2 = cs[b + ((tc + 32) ^ dd)];
      float4 c3 = cs[b + ((tc + 48) ^ dd)];
      a0.x = fmaf(zv.x, c0.x, a0.x); a0.y = fmaf(zv.y, c0.y, a0.y);
      a0.z = fmaf(zv.z, c0.z, a0.z); a0.w = fmaf(zv.w, c0.w, a0.w);
      a1.x = fmaf(zv.x, c1.x, a1.x); a1.y = fmaf(zv.y, c1.y, a1.y);
      a1.z = fmaf(zv.z, c1.z, a1.z); a1.w = fmaf(zv.w, c1.w, a1.w);
      a2.x = fmaf(zv.x, c2.x, a2.x); a2.y = fmaf(zv.y, c2.y, a2.y);
      a2.z = fmaf(zv.z, c2.z, a2.z); a2.w = fmaf(zv.w, c2.w, a2.w);
      a3.x = fmaf(zv.x, c3.x, a3.x); a3.y = fmaf(zv.y, c3.y, a3.y);
      a3.z = fmaf(zv.z, c3.z, a3.z); a3.w = fmaf(zv.w, c3.w, a3.w);
    }
    float d0 = (a0.x + a0.y) + (a0.z + a0.w);
    float d1 = (a1.x + a1.y) + (a1.z + a1.w);
    float d2 = (a2.x + a2.y) + (a2.z + a2.w);
    float d3 = (a3.x + a3.y) + (a3.z + a3.w);
    v[ch * 4 + 0] = 100.0f * (2.0f * d0 - cnorm[kbase + tc]);
    v[ch * 4 + 1] = 100.0f * (2.0f * d1 - cnorm[kbase + tc + 16]);
    v[ch * 4 + 2] = 100.0f * (2.0f * d2 - cnorm[kbase + tc + 32]);
    v[ch * 4 + 3] = 100.0f * (2.0f * d3 - cnorm[kbase + tc + 48]);
  }

  float m1 = -3.4e38f, m2 = -3.4e38f;
  int c1 = 0;
#pragma unroll
  for (int j = 0; j < 64; ++j) {
    int col = (j >> 2) * 64 + ((j & 3) << 4) + tc;
    if (v[j] > m1) { m2 = m1; m1 = v[j]; c1 = col; }
    else if (v[j] > m2) { m2 = v[j]; }
  }
#pragma unroll
  for (int m = 1; m < 16; m <<= 1) {
    float om1 = __shfl_xor(m1, m, 64);
    int oc1 = __shfl_xor(c1, m, 64);
    float om2 = __shfl_xor(m2, m, 64);
    if (om1 > m1 || (om1 == m1 && oc1 < c1)) { m2 = fmaxf(m1, om2); m1 = om1; c1 = oc1; }
    else { m2 = fmaxf(om1, m2); }
  }
  const float rowmax = m1;
  const int bcol = c1;
  const bool danger = (m1 - m2) < 0.25f;

  float S = 0.f, T = 0.f;
#pragma unroll
  for (int j = 0; j < 64; ++j) {
    float e = __expf(v[j] - rowmax);
    S += e;
    T = fmaf(e, v[j], T);
    v[j] = e;
  }
#pragma unroll
  for (int m = 1; m < 16; m <<= 1) {
    S += __shfl_xor(S, m, 64);
    T += __shfl_xor(T, m, 64);
  }
  const float invZ = 1.0f / S;
  const float H = rowmax + logf(S) - T * invZ;

  __syncthreads();
  pacc[tid] = 0.f; pacc[tid + 256] = 0.f; pacc[tid + 512] = 0.f; pacc[tid + 768] = 0.f;
  __syncthreads();
#pragma unroll
  for (int j = 0; j < 64; ++j) {
    float pj = v[j] * invZ;
    pj += __shfl_xor(pj, 16, 64);
    pj += __shfl_xor(pj, 32, 64);
    if ((tid & 63) < 16) {
      int col = (j >> 2) * 64 + ((j & 3) << 4) + tc;
      atomicAdd(&pacc[col], pj);
    }
  }
  __syncthreads();
#pragma unroll
  for (int i = 0; i < 4; ++i) {
    int k = tid + i * 256;
    atomicAdd(&ws[k], pacc[k]);
  }

  float sq = 0.f;
#pragma unroll
  for (int jj = 0; jj < 4; ++jj) {
    int dd = jj * 16 + tc;
    float4 zv = zs[tr * 64 + dd];
    float4 cv = *reinterpret_cast<const float4*>(cb + (size_t)bcol * DDIM + dd * 4);
    float4 qv;
    qv.x = zv.x + (cv.x - zv.x);
    qv.y = zv.y + (cv.y - zv.y);
    qv.z = zv.z + (cv.z - zv.z);
    qv.w = zv.w + (cv.w - zv.w);
    *reinterpret_cast<float4*>(out + (size_t)(nbase + tr) * DDIM + dd * 4) = qv;
    float dx = cv.x - zv.x; sq = fmaf(dx, dx, sq);
    dx = cv.y - zv.y; sq = fmaf(dx, dx, sq);
    dx = cv.z - zv.z; sq = fmaf(dx, dx, sq);
    dx = cv.w - zv.w; sq = fmaf(dx, dx, sq);
  }

  if (tc == 0)
    out[OFF_IDX + nbase + tr] = danger ? -(float)(bcol + 1) : (float)bcol;

  float hv = (tc == 0) ? H : 0.f;
#pragma unroll
  for (int m = 1; m < 64; m <<= 1) {
    hv += __shfl_xor(hv, m, 64);
    sq += __shfl_xor(sq, m, 64);
  }
  int wid = tid >> 6;
  if ((tid & 63) == 0) { red[wid] = hv; red[4 + wid] = sq; }
  __syncthreads();
  if (tid == 0) {
    atomicAdd(&ws[1024], (red[0] + red[1]) + (red[2] + red[3]));
    atomicAdd(&ws[1025], (red[4] + red[5]) + (red[6] + red[7]));
  }
}

// ---- re-resolve contested rows with a bit-level numpy emulation ----
__global__ __launch_bounds__(256) void vq_fix(const float* __restrict__ z,
                                              const float* __restrict__ cb,
                                              float* __restrict__ out,
                                              const float* __restrict__ ws) {
  const int lane = threadIdx.x & 63;
  const int gwave = (int)((blockIdx.x * 256 + threadIdx.x) >> 6);
  const int nw = gridDim.x * 4;
  const float* cnorm = ws + 1026;

  for (int row = gwave; row < NROWS; row += nw) {
    float iv = out[OFF_IDX + row];
    if (iv >= 0.0f) continue;
    int kold = (int)(-iv) - 1;
    const float* zr = z + (size_t)row * DDIM;

    float r;
    {
      int h = (lane & 15) >> 3, j = lane & 7;
      const float* xp = zr + h * 128 + j;
      float x = xp[0];
      float sq = x * x; NOFUSE(sq);
      r = sq;
#pragma unroll
      for (int tt = 1; tt < 16; ++tt) {
        x = xp[8 * tt];
        sq = x * x; NOFUSE(sq);
        r = r + sq;
      }
    }
    r = r + __shfl_xor(r, 1, 64);
    r = r + __shfl_xor(r, 2, 64);
    r = r + __shfl_xor(r, 4, 64);
    r = r + __shfl_xor(r, 8, 64);
    const float znorm = __shfl(r, 0, 64);

    float bd = 3.4e38f;
    int bk = 0;
#pragma unroll 1
    for (int t = 0; t < 16; ++t) {
      int k = lane + t * 64;
      const float* cr = cb + (size_t)k * DDIM;
      float acc = 0.0f;
#pragma unroll 8
      for (int d = 0; d < 256; ++d) acc = fmaf(zr[d], cr[d], acc);
      float dist = (znorm - 2.0f * acc) + cnorm[k];
      if (dist < bd) { bd = dist; bk = k; }
    }
#pragma unroll
    for (int m = 1; m < 64; m <<= 1) {
      float od = __shfl_xor(bd, m, 64);
      int ok = __shfl_xor(bk, m, 64);
      if (od < bd || (od == bd && ok < bk)) { bd = od; bk = ok; }
    }

    if (bk != kold) {
      const float* cr = cb + (size_t)bk * DDIM;
#pragma unroll
      for (int i = 0; i < 4; ++i) {
        int d0 = lane + i * 64;
        float zd = zr[d0], cd = cr[d0];
        out[(size_t)row * DDIM + d0] = zd + (cd - zd);
      }
    }
    if (lane == 0) out[OFF_IDX + row] = (float)bk;
  }
}

__global__ __launch_bounds__(1024) void vq_final(float* __restrict__ out,
                                                 const float* __restrict__ ws) {
  __shared__ float red[1024];
  int t = threadIdx.x;
  float a = ws[t] * (1.0f / 32768.0f);
  red[t] = a * logf(a + 1e-5f);
  __syncthreads();
  for (int s = 512; s > 0; s >>= 1) {
    if (t < s) red[t] += red[t + s];
    __syncthreads();
  }
  if (t == 0) {
    float avg_entropy = -red[0];
    float sample_entropy = ws[1024] * (1.0f / 32768.0f);
    float m = ws[1025] * (1.0f / 8388608.0f);
    out[OFF_COMMIT] = 0.25f * m;
    out[OFF_EMBED] = m;
    out[OFF_ENT] = 0.1f * (sample_entropy - avg_entropy);
  }
}

extern "C" void kernel_launch(void* const* d_in, const int* in_sizes, int n_in,
                              void* d_out, int out_size, void* d_ws, size_t ws_size,
                              hipStream_t stream) {
  const float* z = (const float*)d_in[0];
  const float* cb = (const float*)d_in[1];
  float* out = (float*)d_out;
  float* ws = (float*)d_ws;

  vq_prep<<<64, 256, 0, stream>>>(cb, ws);
  if (ws_size >= WS_NEED_BYTES) {
    vq_cbimg<<<256, 256, 0, stream>>>(cb, ws);
    vq_main2<<<NROWS / 32, 512, 0, stream>>>(
        z, cb, (const unsigned short*)(ws + WS_IMG_F), out, ws);
  } else {
    vq_main_fb<<<NROWS / 16, 256, 0, stream>>>(z, cb, out, ws);
  }
  vq_fix<<<256, 256, 0, stream>>>(z, cb, out, ws);
  vq_final<<<1, 1024, 0, stream>>>(out, ws);
}